// Round 2
// 424.181 us; speedup vs baseline: 1.0052x; 1.0052x over previous
//
#include <hip/hip_runtime.h>

// waspGridSpatialIntegral: out[:,0] = cumsum_x(in[:,0]), out[:,1] = cumsum_y(in[:,1])
// B=128, W=512, fp32. Memory-bound: 256 MiB in + 256 MiB out; floor ~82-85 us.
// Nontemporal loads/stores (streaming, zero reuse -> don't thrash L2) and a
// 16-deep double-buffered pipeline on the y-cumsum path (was: issue 8, wait-all).

#define W 512
#define BATCH 128
#define NB1 256  // channel-1 (y-cumsum) blocks, scheduled first (long-running)

// clang native vector type: __builtin_nontemporal_* accepts this, not HIP float4.
typedef float v4f __attribute__((ext_vector_type(4)));

// 16 nontemporal column loads, rows [r0, r0+16)
#define LD16(dst, r0)                                                         \
    _Pragma("unroll")                                                         \
    for (int j = 0; j < 16; ++j)                                              \
        dst[j] = __builtin_nontemporal_load(ip + (size_t)((r0) + j) * W);

// accumulate + 16 nontemporal column stores, rows [r0, r0+16)
#define PR16(src, r0)                                                         \
    _Pragma("unroll")                                                         \
    for (int j = 0; j < 16; ++j) {                                            \
        sum += src[j];                                                        \
        __builtin_nontemporal_store(sum, op + (size_t)((r0) + j) * W);        \
    }

__global__ __launch_bounds__(256) void spatial_integral_kernel(
    const float* __restrict__ in, float* __restrict__ out) {
    const int bid = blockIdx.x;

    if (bid < NB1) {
        // ---- channel 1: cumsum over y (columns). One thread per column. ----
        // Block covers 256 consecutive columns of one image's channel 1.
        // Double-buffered 16-row batches: loads for batch i+1 are in flight
        // while batch i is accumulated+stored (2 batches = 8 KiB/wave in flight).
        const int b = bid >> 1;
        const int x = (bid & 1) * 256 + threadIdx.x;
        const size_t base = (size_t)b * 2 * W * W + (size_t)W * W + (size_t)x;
        const float* ip = in  + base;
        float*       op = out + base;

        float sum = 0.0f;
        float A[16], Bv[16];
        LD16(A, 0);
        #pragma unroll 1
        for (int y0 = 0; y0 <= W - 64; y0 += 32) {
            LD16(Bv, y0 + 16);   // prefetch batch i+1
            PR16(A,  y0);        // process batch i (its loads landed last phase)
            LD16(A,  y0 + 32);   // prefetch batch i+2
            PR16(Bv, y0 + 16);   // process batch i+1
        }
        // A holds rows [W-32, W-16)
        LD16(Bv, W - 16);
        PR16(A,  W - 32);
        PR16(Bv, W - 16);
    } else {
        // ---- channel 0: cumsum over x (rows). One wave per 512-float row. ----
        const int rb   = bid - NB1;
        const int wave = threadIdx.x >> 6;
        const int lane = threadIdx.x & 63;
        const int row  = rb * 4 + wave;        // [0, B*W)
        const int b    = row >> 9;             // row / 512
        const int y    = row & 511;
        const size_t base = (size_t)b * 2 * W * W + (size_t)y * W;  // channel 0
        const v4f* ip4 = (const v4f*)(in + base);
        v4f*       op4 = (v4f*)(out + base);

        const v4f a = __builtin_nontemporal_load(ip4 + lane * 2);
        const v4f c = __builtin_nontemporal_load(ip4 + lane * 2 + 1);
        float p[8] = {a.x, a.y, a.z, a.w, c.x, c.y, c.z, c.w};
        #pragma unroll
        for (int j = 1; j < 8; ++j) p[j] += p[j - 1];

        // exclusive scan of lane totals across the 64-lane wave
        const float tot = p[7];
        float scan = tot;
        #pragma unroll
        for (int off = 1; off < 64; off <<= 1) {
            const float n = __shfl_up(scan, off, 64);
            if (lane >= off) scan += n;
        }
        const float excl = scan - tot;

        #pragma unroll
        for (int j = 0; j < 8; ++j) p[j] += excl;
        v4f lo, hi;
        lo.x = p[0]; lo.y = p[1]; lo.z = p[2]; lo.w = p[3];
        hi.x = p[4]; hi.y = p[5]; hi.z = p[6]; hi.w = p[7];
        __builtin_nontemporal_store(lo, op4 + lane * 2);
        __builtin_nontemporal_store(hi, op4 + lane * 2 + 1);
    }
}

extern "C" void kernel_launch(void* const* d_in, const int* in_sizes, int n_in,
                              void* d_out, int out_size, void* d_ws, size_t ws_size,
                              hipStream_t stream) {
    const float* in = (const float*)d_in[0];
    float* out = (float*)d_out;
    // ch1 blocks first (long-running), then B*W/4 = 16384 ch0 row-blocks.
    const int nblocks = NB1 + (BATCH * W) / 4;
    spatial_integral_kernel<<<dim3(nblocks), dim3(256), 0, stream>>>(in, out);
}